// Round 16
// baseline (181.273 us; speedup 1.0000x reference)
//
#include <hip/hip_runtime.h>
#include <hip/hip_bf16.h>

typedef __bf16 bf16;
typedef __attribute__((ext_vector_type(8))) __bf16 bf16x8;
typedef __attribute__((ext_vector_type(2))) __bf16 bf16x2;
typedef __attribute__((ext_vector_type(4))) float f32x4;
typedef __attribute__((ext_vector_type(4))) unsigned int uint4v;

#define C_NODES 63
#define F_DIM   250
#define NEG_SLOPE 0.2f
#define BS 8               // batches per persistent block; grid 512

// LDS map (41472 B -> 2 blocks/CU):
//   [0, 32768)      AFR: bf16 MFMA A-fragments of X (swzA). Rewritten per
//                   batch; NaN-guard zero slots persist.
//   [32768, 33024)  AS: a_s[64] f32
//   [33024, 33280)  AD: a_d[64] f32
//   [33280, 41472)  ALPHA: alpha[64][64] bf16 (swz, 128 B rows)
#define OFF_AS    32768
#define OFF_AD    33024
#define ALPHA_B   33280
#define LDS_BYTES 41472

__device__ __forceinline__ int swz(int a) { return a ^ ((a >> 3) & 0x70); }
// A-frag swizzle: bank-uniform staging writes, bijective reads.
__device__ __forceinline__ int swzA(int a) {
    return a ^ ((((a >> 8) & 3) ^ ((a >> 10) & 3)) << 4) ^ (((a >> 12) & 1) << 6);
}

// lgkm-only barrier: global loads/stores (vmcnt) stay in flight across it.
__device__ __forceinline__ void bar_lgkm() {
    asm volatile("s_waitcnt lgkmcnt(0)" ::: "memory");
    __builtin_amdgcn_s_barrier();
    __builtin_amdgcn_sched_barrier(0);
}

// Pack W (250x250 f32) into bf16 MFMA-B fragment order, padded to 256x256.
// Columns 250/251 hold ws = W@att_src and wd = W@att_dst, so GEMM1 emits the
// per-node scores a_s, a_d directly. Rows k>=250 are zero (kills A-garbage).
extern "C" __global__ __launch_bounds__(256)
void gat_prep(const float* __restrict__ W, const float* __restrict__ att_src,
              const float* __restrict__ att_dst, bf16* __restrict__ Wp) {
    int i = blockIdx.x * 256 + threadIdx.x;   // 0..65535
    int tile = i >> 9;
    int ln   = (i >> 3) & 63;
    int j    = i & 7;
    int kt = tile >> 4, nt = tile & 15;
    int k = kt * 32 + (ln >> 4) * 8 + j;
    int n = nt * 16 + (ln & 15);
    float v = 0.f;
    if (k < F_DIM) {
        if (n < F_DIM) {
            v = W[k * F_DIM + n];
        } else if (n == F_DIM || n == F_DIM + 1) {
            const float* att = (n == F_DIM) ? att_src : att_dst;
            float s = 0.f;
            for (int o = 0; o < F_DIM; ++o) s = fmaf(W[k * F_DIM + o], att[o], s);
            v = s;
        }
    }
    Wp[i] = (bf16)v;
}

// Stage one prefetch pair (iterations i0, i0+1) into AFR.
__device__ __forceinline__ void afr_write_pair(unsigned char* smem, int tid,
                                               int i0, const float2 pf[2][4]) {
#pragma unroll
    for (int it = 0; it < 2; ++it) {
        int idx = tid + (i0 + it) * 512;
        if (idx < 2016) {
            int r = idx >> 5, g = idx & 31;
            int dl = (r & 15) | ((g & 3) << 4);
            int base = swzA((((r >> 4) * 8 + (g >> 2)) << 10) + dl * 16);
            if (g < 31) {
                bf16x8 pk8 = { (bf16)pf[it][0].x, (bf16)pf[it][0].y,
                               (bf16)pf[it][1].x, (bf16)pf[it][1].y,
                               (bf16)pf[it][2].x, (bf16)pf[it][2].y,
                               (bf16)pf[it][3].x, (bf16)pf[it][3].y };
                *(bf16x8*)(smem + base) = pk8;
            } else {
                bf16x2 pk2 = { (bf16)pf[it][0].x, (bf16)pf[it][0].y };
                *(bf16x2*)(smem + base) = pk2;
            }
        }
    }
}

__device__ __forceinline__ void pf_load_pair(const float* xn, int tid, int i0,
                                             float2 pf[2][4]) {
#pragma unroll
    for (int it = 0; it < 2; ++it) {
        int idx = tid + (i0 + it) * 512;
        if (idx < 2016) {
            int r = idx >> 5, g = idx & 31;
            const float* src = xn + r * F_DIM + g * 8;
            pf[it][0] = *(const float2*)(src);
            if (g < 31) {
                pf[it][1] = *(const float2*)(src + 2);
                pf[it][2] = *(const float2*)(src + 4);
                pf[it][3] = *(const float2*)(src + 6);
            }
        }
    }
}

// 512 threads = 8 waves; wave w owns output cols [w*32, w*32+32).
// Persistent BS=8; phases A|B|D, 3 lgkm-only barriers, 16+16-reg split pf.
// ONE accumulator array (gacc) shared by GEMM1 and GEMM2: halves AGPR use
// (64 -> 32), freeing arch-VGPR headroom that r14/r15 spilled for.
extern "C" __global__ __launch_bounds__(512, 4)
void gat_main(const float* __restrict__ x, const bf16* __restrict__ Wp,
              const float* __restrict__ bias, float* __restrict__ out)
{
    __shared__ __align__(16) unsigned char smem[LDS_BYTES];
    const int tid  = threadIdx.x;
    const int lane = tid & 63;
    const int w    = tid >> 6;        // wave id 0..7
    const int fl   = lane & 15;
    const int fh   = lane >> 4;
    const int b0   = blockIdx.x * BS;

    const bf16x8* wpv = (const bf16x8*)Wp;

    // bias (2 regs, held)
    float bv0, bv1;
    { int f = w * 32 + fl;      bv0 = (f < F_DIM) ? bias[f] : 0.f;
      f += 16;                  bv1 = (f < F_DIM) ? bias[f] : 0.f; }

    // NaN-guard (ONCE): zero the A-frag slots the scatter never writes.
    if (tid < 64) {
        int base = swzA((((tid >> 4) * 8 + 7) << 10) + (48 + (tid & 15)) * 16);
        *(unsigned int*)(smem + base + 4) = 0u;
        *(unsigned long long*)(smem + base + 8) = 0ull;
    } else if (tid < 96) {
        int idx = tid - 64;
        int base = swzA(((24 + (idx >> 2)) << 10) + ((((idx & 3) << 4) | 15) * 16));
        *(f32x4*)(smem + base) = (f32x4){0.f, 0.f, 0.f, 0.f};
    }

    // prime: stage b0 -> AFR
    {
        const float* xb = x + (size_t)b0 * (C_NODES * F_DIM);
        float2 pfp[2][4];
        pf_load_pair(xb, tid, 0, pfp);
        afr_write_pair(smem, tid, 0, pfp);
        pf_load_pair(xb, tid, 2, pfp);
        afr_write_pair(smem, tid, 2, pfp);
    }
    __syncthreads();

#pragma unroll 1
    for (int i = 0; i < BS; ++i) {
        const int b = b0 + i;
        const float* xn = x + (size_t)(b + 1) * (C_NODES * F_DIM);
        const bool pfen = (i + 1 < BS);

        // ---- A: issue pf1; GEMM1; AS/AD extract; bar1 ----
        float2 pf1[2][4];
        if (pfen) pf_load_pair(xn, tid, 0, pf1);

        f32x4 gacc[4][2];
#pragma unroll
        for (int mt = 0; mt < 4; ++mt) {
            gacc[mt][0] = (f32x4){0.f, 0.f, 0.f, 0.f};
            gacc[mt][1] = (f32x4){0.f, 0.f, 0.f, 0.f};
        }
#pragma unroll 1
        for (int kt = 0; kt < 8; ++kt) {
            bf16x8 bw0 = wpv[(kt * 16 + w * 2)     * 64 + lane];
            bf16x8 bw1 = wpv[(kt * 16 + w * 2 + 1) * 64 + lane];
#pragma unroll
            for (int mt = 0; mt < 4; ++mt) {
                bf16x8 af = *(const bf16x8*)(smem + swzA(((mt * 8 + kt) << 10) + lane * 16));
                gacc[mt][0] = __builtin_amdgcn_mfma_f32_16x16x32_bf16(af, bw0, gacc[mt][0], 0, 0, 0);
                gacc[mt][1] = __builtin_amdgcn_mfma_f32_16x16x32_bf16(af, bw1, gacc[mt][1], 0, 0, 0);
            }
        }
        if (w == 7 && (fl == 10 || fl == 11)) {      // cols 250 / 251
            float* dst = (float*)(smem + (fl == 10 ? OFF_AS : OFF_AD));
#pragma unroll
            for (int mt = 0; mt < 4; ++mt) {
                f32x4 v = gacc[mt][1];
#pragma unroll
                for (int q = 0; q < 4; ++q) dst[mt * 16 + fh * 4 + q] = v[q];
            }
        }
        bar_lgkm();   // bar1: AFR reads + AS/AD writes done

        // ---- B: issue pf2; pack+transpose H (gacc dies); softmax;
        //         write pf1 -> AFR; bar2 ----
        float2 pf2[2][4];
        if (pfen) pf_load_pair(xn, tid, 2, pf2);

        unsigned int pk[4][2][2];
#pragma unroll
        for (int mt = 0; mt < 4; ++mt)
#pragma unroll
            for (int nti = 0; nti < 2; ++nti) {
                f32x4 v = gacc[mt][nti];
                bf16x2 p0 = { (bf16)v.x, (bf16)v.y };
                bf16x2 p1 = { (bf16)v.z, (bf16)v.w };
                pk[mt][nti][0] = __builtin_bit_cast(unsigned int, p0);
                pk[mt][nti][1] = __builtin_bit_cast(unsigned int, p1);
            }
        const int LA = ((fh & 1) << 5) + fl;
        const int LB = LA + 16;
        const bool fhHi = (fh & 2) != 0;
        uint4v hb[2][2];
#pragma unroll
        for (int nti = 0; nti < 2; ++nti)
#pragma unroll
            for (int kt2 = 0; kt2 < 2; ++kt2) {
                unsigned int u[4];
#pragma unroll
                for (int h = 0; h < 2; ++h) {
                    unsigned int a0 = __shfl(pk[kt2 * 2][nti][h],     LA);
                    unsigned int a1 = __shfl(pk[kt2 * 2 + 1][nti][h], LA);
                    u[h] = fhHi ? a1 : a0;
                    unsigned int c0 = __shfl(pk[kt2 * 2][nti][h],     LB);
                    unsigned int c1 = __shfl(pk[kt2 * 2 + 1][nti][h], LB);
                    u[2 + h] = fhHi ? c1 : c0;
                }
                hb[nti][kt2] = (uint4v){u[0], u[1], u[2], u[3]};
            }
        // softmax (block-wide, once): thread=(d=tid>>3, c=tid&7)
        {
            const float* AS  = (const float*)(smem + OFF_AS);
            const float* ADp = (const float*)(smem + OFF_AD);
            int d = tid >> 3;
            int c = tid & 7;
            float ad_v = ADp[d];
            f32x4 a0 = *(const f32x4*)(AS + c * 8);
            f32x4 a1 = *(const f32x4*)(AS + c * 8 + 4);
            float p[8];
#pragma unroll
            for (int k = 0; k < 4; ++k) {
                float e;
                e = a0[k] + ad_v; p[k]     = (e > 0.f) ? e : NEG_SLOPE * e;
                e = a1[k] + ad_v; p[4 + k] = (e > 0.f) ? e : NEG_SLOPE * e;
            }
            if (c == 7) p[7] = -3.0e38f;   // s=63 excluded (63 sources)
            float md = p[0];
#pragma unroll
            for (int k = 1; k < 8; ++k) md = fmaxf(md, p[k]);
            md = fmaxf(md, __shfl_xor(md, 1));
            md = fmaxf(md, __shfl_xor(md, 2));
            md = fmaxf(md, __shfl_xor(md, 4));
            float sum = 0.f;
#pragma unroll
            for (int k = 0; k < 8; ++k) { p[k] = __expf(p[k] - md); sum += p[k]; }
            sum += __shfl_xor(sum, 1);
            sum += __shfl_xor(sum, 2);
            sum += __shfl_xor(sum, 4);
            float rz = 1.f / sum;
            bf16x8 pkv;
#pragma unroll
            for (int k = 0; k < 8; ++k) pkv[k] = (bf16)(p[k] * rz);
            *(bf16x8*)(smem + swz(ALPHA_B + d * 128 + c * 16)) = pkv;
        }
        if (pfen) afr_write_pair(smem, tid, 0, pf1);   // pf1 dies here
        bar_lgkm();   // bar2: alpha + AFR half ready

        // ---- D: GEMM2 (gacc reused); write pf2 -> AFR; stores; bar3 ----
#pragma unroll
        for (int mt = 0; mt < 4; ++mt) {
            gacc[mt][0] = (f32x4){0.f, 0.f, 0.f, 0.f};
            gacc[mt][1] = (f32x4){0.f, 0.f, 0.f, 0.f};
        }
#pragma unroll
        for (int ks = 0; ks < 2; ++ks) {
            int kk = ks * 32 + fh * 8;
            bf16x8 h0 = __builtin_bit_cast(bf16x8, hb[0][ks]);
            bf16x8 h1 = __builtin_bit_cast(bf16x8, hb[1][ks]);
#pragma unroll
            for (int mt = 0; mt < 4; ++mt) {
                bf16x8 aal = *(const bf16x8*)(smem + swz(ALPHA_B + (mt * 16 + fl) * 128 + kk * 2));
                gacc[mt][0] = __builtin_amdgcn_mfma_f32_16x16x32_bf16(aal, h0, gacc[mt][0], 0, 0, 0);
                gacc[mt][1] = __builtin_amdgcn_mfma_f32_16x16x32_bf16(aal, h1, gacc[mt][1], 0, 0, 0);
            }
        }
        if (pfen) afr_write_pair(smem, tid, 2, pf2);   // pf2 dies here

        float* ob = out + (size_t)b * (C_NODES * F_DIM);
#pragma unroll
        for (int mt = 0; mt < 4; ++mt) {
#pragma unroll
            for (int q = 0; q < 4; ++q) {
                int r = mt * 16 + fh * 4 + q;
                if (r < C_NODES) {
                    int f = w * 32 + fl;
                    ob[r * F_DIM + f] = gacc[mt][0][q] + bv0;
                    f += 16;
                    if (f < F_DIM) ob[r * F_DIM + f] = gacc[mt][1][q] + bv1;
                }
            }
        }
        bar_lgkm();   // bar3: AFR[b+1] + alpha reads drained; stores fly on
    }
}

extern "C" void kernel_launch(void* const* d_in, const int* in_sizes, int n_in,
                              void* d_out, int out_size, void* d_ws, size_t ws_size,
                              hipStream_t stream) {
    const float* x       = (const float*)d_in[0];
    const float* W       = (const float*)d_in[1];
    const float* att_src = (const float*)d_in[2];
    const float* att_dst = (const float*)d_in[3];
    const float* bias    = (const float*)d_in[4];
    float* out = (float*)d_out;
    bf16* Wp = (bf16*)d_ws;   // 65536 bf16 = 128 KB packed W (+score cols)

    gat_prep<<<256, 256, 0, stream>>>(W, att_src, att_dst, Wp);
    gat_main<<<512, 512, 0, stream>>>(x, Wp, bias, out);
}

// Round 17
// 139.632 us; speedup vs baseline: 1.2982x; 1.2982x over previous
//
#include <hip/hip_runtime.h>
#include <hip/hip_bf16.h>

typedef __bf16 bf16;
typedef __attribute__((ext_vector_type(8))) __bf16 bf16x8;
typedef __attribute__((ext_vector_type(2))) __bf16 bf16x2;
typedef __attribute__((ext_vector_type(4))) float f32x4;
typedef __attribute__((ext_vector_type(4))) unsigned int uint4v;

#define C_NODES 63
#define F_DIM   250
#define NEG_SLOPE 0.2f
#define BS 8               // batches per persistent block; grid 512

// LDS map (74240 B -> 2 blocks/CU):
//   [0, 65520)      SLAB: X as f32, 63 rows x 1040 B stride (260 f32).
//                   DMA fills bytes [0,992) per row; cols 248/249 reg-staged
//                   at [992,1000); cols 250-255 zeroed once at [1000,1024).
//   [65536, 65792)  AS: a_s[64] f32
//   [65792, 66048)  AD: a_d[64] f32
//   [66048, 74240)  ALPHA: alpha[64][64] bf16 (swz, 128 B rows)
#define ROWB      1040
#define SLAB      0
#define OFF_AS    65536
#define OFF_AD    65792
#define ALPHA_B   66048
#define LDS_BYTES 74240

__device__ __forceinline__ int swz(int a) { return a ^ ((a >> 3) & 0x70); }

typedef const __attribute__((address_space(1))) void* gas_t;
typedef __attribute__((address_space(3))) void* las_t;
__device__ __forceinline__ void dma16(const void* g, void* l) {
    __builtin_amdgcn_global_load_lds((gas_t)g, (las_t)l, 16, 0, 0);
}

// lgkm-only barrier: DMA/stores (vmcnt) stay in flight across phases.
__device__ __forceinline__ void bar_lgkm() {
    asm volatile("s_waitcnt lgkmcnt(0)" ::: "memory");
    __builtin_amdgcn_s_barrier();
    __builtin_amdgcn_sched_barrier(0);
}

// Pack W (250x250 f32) into bf16 MFMA-B fragment order, padded to 256x256.
// Columns 250/251 hold ws = W@att_src and wd = W@att_dst, so GEMM1 emits the
// per-node scores a_s, a_d directly. Rows k>=250 are zero (kills A-garbage).
extern "C" __global__ __launch_bounds__(256)
void gat_prep(const float* __restrict__ W, const float* __restrict__ att_src,
              const float* __restrict__ att_dst, bf16* __restrict__ Wp) {
    int i = blockIdx.x * 256 + threadIdx.x;   // 0..65535
    int tile = i >> 9;
    int ln   = (i >> 3) & 63;
    int j    = i & 7;
    int kt = tile >> 4, nt = tile & 15;
    int k = kt * 32 + (ln >> 4) * 8 + j;
    int n = nt * 16 + (ln & 15);
    float v = 0.f;
    if (k < F_DIM) {
        if (n < F_DIM) {
            v = W[k * F_DIM + n];
        } else if (n == F_DIM || n == F_DIM + 1) {
            const float* att = (n == F_DIM) ? att_src : att_dst;
            float s = 0.f;
            for (int o = 0; o < F_DIM; ++o) s = fmaf(W[k * F_DIM + o], att[o], s);
            v = s;
        }
    }
    Wp[i] = (bf16)v;
}

// 512 threads = 8 waves; wave w owns output cols [w*32, w*32+32).
// r13 DMA pipeline + merged softmax (3 barriers) + shared gacc + unroll-2.
extern "C" __global__ __launch_bounds__(512, 4)
void gat_main(const float* __restrict__ x, const bf16* __restrict__ Wp,
              const float* __restrict__ bias, float* __restrict__ out)
{
    __shared__ __align__(16) unsigned char smem[LDS_BYTES];
    const int tid  = threadIdx.x;
    const int lane = tid & 63;
    const int w    = tid >> 6;        // wave id 0..7
    const int fl   = lane & 15;
    const int fh   = lane >> 4;
    const int b0   = blockIdx.x * BS;

    const bf16x8* wpv = (const bf16x8*)Wp;

    // bias (2 regs, held)
    float bv0, bv1;
    { int f = w * 32 + fl;      bv0 = (f < F_DIM) ? bias[f] : 0.f;
      f += 16;                  bv1 = (f < F_DIM) ? bias[f] : 0.f; }

    // zero cols 250-255 of every slab row (once; DMA/tail never re-dirty)
    if (tid < 63) {
        *(unsigned long long*)(smem + SLAB + tid * ROWB + 1000) = 0ull;
        *(f32x4*)(smem + SLAB + tid * ROWB + 1008) = (f32x4){0.f, 0.f, 0.f, 0.f};
    }

    // prime batch b0: DMA rows (wave w stages rows w*8..w*8+7) + reg tail
    {
        const float* xb = x + (size_t)b0 * (C_NODES * F_DIM);
        float2 tl0 = {0.f, 0.f};
        if (tid < 63) tl0 = *(const float2*)(xb + tid * F_DIM + 248);
#pragma unroll
        for (int rr = 0; rr < 8; ++rr) {
            int r = w * 8 + rr;
            if (r < 63 && lane < 62)
                dma16(xb + r * F_DIM + lane * 4, smem + SLAB + r * ROWB);
        }
        if (tid < 63) *(float2*)(smem + SLAB + tid * ROWB + 992) = tl0;
    }
    asm volatile("s_waitcnt vmcnt(0)" ::: "memory");
    bar_lgkm();      // slab[b0] ready

#pragma unroll 1
    for (int i = 0; i < BS; ++i) {
        const int b = b0 + i;
        const float* xnext = x + (size_t)(b + 1) * (C_NODES * F_DIM);

        // tail cols 248/249 of b+1: load EARLY so its wait is vmcnt(N), not 0
        float2 tl = {0.f, 0.f};
        if (i + 1 < BS && tid < 63) tl = *(const float2*)(xnext + tid * F_DIM + 248);

        // ---- A: GEMM1  H'[64][256] = X @ Wp ; cols 250/251 = a_s/a_d;
        //         w7 writes AS/AD before bar1 ----
        f32x4 gacc[4][2];
#pragma unroll
        for (int mt = 0; mt < 4; ++mt) {
            gacc[mt][0] = (f32x4){0.f, 0.f, 0.f, 0.f};
            gacc[mt][1] = (f32x4){0.f, 0.f, 0.f, 0.f};
        }
#pragma unroll 2
        for (int kt = 0; kt < 8; ++kt) {
            bf16x8 bw0 = wpv[(kt * 16 + w * 2)     * 64 + lane];
            bf16x8 bw1 = wpv[(kt * 16 + w * 2 + 1) * 64 + lane];
#pragma unroll
            for (int mt = 0; mt < 4; ++mt) {
                int row = mt * 16 + fl;
                bf16x8 af;
                if (row < C_NODES) {
                    const f32x4* p = (const f32x4*)(smem + SLAB + row * ROWB + kt * 128 + fh * 32);
                    f32x4 lo = p[0], hi = p[1];
                    af = (bf16x8){ (bf16)lo.x, (bf16)lo.y, (bf16)lo.z, (bf16)lo.w,
                                   (bf16)hi.x, (bf16)hi.y, (bf16)hi.z, (bf16)hi.w };
                } else {
                    af = (bf16x8){(bf16)0.f,(bf16)0.f,(bf16)0.f,(bf16)0.f,
                                  (bf16)0.f,(bf16)0.f,(bf16)0.f,(bf16)0.f};
                }
                gacc[mt][0] = __builtin_amdgcn_mfma_f32_16x16x32_bf16(af, bw0, gacc[mt][0], 0, 0, 0);
                gacc[mt][1] = __builtin_amdgcn_mfma_f32_16x16x32_bf16(af, bw1, gacc[mt][1], 0, 0, 0);
            }
        }
        if (w == 7 && (fl == 10 || fl == 11)) {      // cols 250 / 251
            float* dst = (float*)(smem + (fl == 10 ? OFF_AS : OFF_AD));
#pragma unroll
            for (int mt = 0; mt < 4; ++mt) {
                f32x4 v = gacc[mt][1];
#pragma unroll
                for (int q = 0; q < 4; ++q) dst[mt * 16 + fh * 4 + q] = v[q];
            }
        }
        bar_lgkm();   // bar1: slab reads + AS/AD writes done

        // ---- B: DMA(b+1); pack+transpose H; softmax; tail write; bar2 ----
        if (i + 1 < BS) {
#pragma unroll
            for (int rr = 0; rr < 8; ++rr) {
                int r = w * 8 + rr;
                if (r < 63 && lane < 62)
                    dma16(xnext + r * F_DIM + lane * 4, smem + SLAB + r * ROWB);
            }
        }
        // pack H C-frags to bf16 pairs, shuffle-transpose to GEMM2 B-frags
        unsigned int pk[4][2][2];
#pragma unroll
        for (int mt = 0; mt < 4; ++mt)
#pragma unroll
            for (int nti = 0; nti < 2; ++nti) {
                f32x4 v = gacc[mt][nti];
                bf16x2 p0 = { (bf16)v.x, (bf16)v.y };
                bf16x2 p1 = { (bf16)v.z, (bf16)v.w };
                pk[mt][nti][0] = __builtin_bit_cast(unsigned int, p0);
                pk[mt][nti][1] = __builtin_bit_cast(unsigned int, p1);
            }
        const int LA = ((fh & 1) << 5) + fl;
        const int LB = LA + 16;
        const bool fhHi = (fh & 2) != 0;
        uint4v hb[2][2];
#pragma unroll
        for (int nti = 0; nti < 2; ++nti)
#pragma unroll
            for (int kt2 = 0; kt2 < 2; ++kt2) {
                unsigned int u[4];
#pragma unroll
                for (int h = 0; h < 2; ++h) {
                    unsigned int a0 = __shfl(pk[kt2 * 2][nti][h],     LA);
                    unsigned int a1 = __shfl(pk[kt2 * 2 + 1][nti][h], LA);
                    u[h] = fhHi ? a1 : a0;
                    unsigned int c0 = __shfl(pk[kt2 * 2][nti][h],     LB);
                    unsigned int c1 = __shfl(pk[kt2 * 2 + 1][nti][h], LB);
                    u[2 + h] = fhHi ? c1 : c0;
                }
                hb[nti][kt2] = (uint4v){u[0], u[1], u[2], u[3]};
            }
        // softmax (block-wide, once): thread=(d=tid>>3, c=tid&7)
        {
            const float* AS  = (const float*)(smem + OFF_AS);
            const float* ADp = (const float*)(smem + OFF_AD);
            int d = tid >> 3;
            int c = tid & 7;
            float ad_v = ADp[d];
            f32x4 a0 = *(const f32x4*)(AS + c * 8);
            f32x4 a1 = *(const f32x4*)(AS + c * 8 + 4);
            float p[8];
#pragma unroll
            for (int k = 0; k < 4; ++k) {
                float e;
                e = a0[k] + ad_v; p[k]     = (e > 0.f) ? e : NEG_SLOPE * e;
                e = a1[k] + ad_v; p[4 + k] = (e > 0.f) ? e : NEG_SLOPE * e;
            }
            if (c == 7) p[7] = -3.0e38f;   // s=63 excluded (63 sources)
            float md = p[0];
#pragma unroll
            for (int k = 1; k < 8; ++k) md = fmaxf(md, p[k]);
            md = fmaxf(md, __shfl_xor(md, 1));
            md = fmaxf(md, __shfl_xor(md, 2));
            md = fmaxf(md, __shfl_xor(md, 4));
            float sum = 0.f;
#pragma unroll
            for (int k = 0; k < 8; ++k) { p[k] = __expf(p[k] - md); sum += p[k]; }
            sum += __shfl_xor(sum, 1);
            sum += __shfl_xor(sum, 2);
            sum += __shfl_xor(sum, 4);
            float rz = 1.f / sum;
            bf16x8 pkv;
#pragma unroll
            for (int k = 0; k < 8; ++k) pkv[k] = (bf16)(p[k] * rz);
            *(bf16x8*)(smem + swz(ALPHA_B + d * 128 + c * 16)) = pkv;
        }
        if (i + 1 < BS && tid < 63)
            *(float2*)(smem + SLAB + tid * ROWB + 992) = tl;
        bar_lgkm();   // bar2: alpha + tail visible (DMA still flying)

        // ---- D: GEMM2 (alpha LDS x transposed-H regs, gacc reused);
        //         stores; vmcnt-gated bar3 ----
#pragma unroll
        for (int mt = 0; mt < 4; ++mt) {
            gacc[mt][0] = (f32x4){0.f, 0.f, 0.f, 0.f};
            gacc[mt][1] = (f32x4){0.f, 0.f, 0.f, 0.f};
        }
#pragma unroll
        for (int ks = 0; ks < 2; ++ks) {
            int kk = ks * 32 + fh * 8;
            bf16x8 h0 = __builtin_bit_cast(bf16x8, hb[0][ks]);
            bf16x8 h1 = __builtin_bit_cast(bf16x8, hb[1][ks]);
#pragma unroll
            for (int mt = 0; mt < 4; ++mt) {
                bf16x8 aal = *(const bf16x8*)(smem + swz(ALPHA_B + (mt * 16 + fl) * 128 + kk * 2));
                gacc[mt][0] = __builtin_amdgcn_mfma_f32_16x16x32_bf16(aal, h0, gacc[mt][0], 0, 0, 0);
                gacc[mt][1] = __builtin_amdgcn_mfma_f32_16x16x32_bf16(aal, h1, gacc[mt][1], 0, 0, 0);
            }
        }
        float* ob = out + (size_t)b * (C_NODES * F_DIM);
#pragma unroll
        for (int mt = 0; mt < 4; ++mt) {
#pragma unroll
            for (int q = 0; q < 4; ++q) {
                int r = mt * 16 + fh * 4 + q;
                if (r < C_NODES) {
                    int f = w * 32 + fl;
                    ob[r * F_DIM + f] = gacc[mt][0][q] + bv0;
                    f += 16;
                    if (f < F_DIM) ob[r * F_DIM + f] = gacc[mt][1][q] + bv1;
                }
            }
        }
        if (i + 1 < BS) {
            // 8 DMA ops are OLDER than the 32 stores just issued: vmcnt(32)
            // == "all DMA landed, stores may keep flying".
            asm volatile("s_waitcnt vmcnt(32)" ::: "memory");
            bar_lgkm();   // bar3: slab[b+1] visible to all waves
        }
    }
}

extern "C" void kernel_launch(void* const* d_in, const int* in_sizes, int n_in,
                              void* d_out, int out_size, void* d_ws, size_t ws_size,
                              hipStream_t stream) {
    const float* x       = (const float*)d_in[0];
    const float* W       = (const float*)d_in[1];
    const float* att_src = (const float*)d_in[2];
    const float* att_dst = (const float*)d_in[3];
    const float* bias    = (const float*)d_in[4];
    float* out = (float*)d_out;
    bf16* Wp = (bf16*)d_ws;   // 65536 bf16 = 128 KB packed W (+score cols)

    gat_prep<<<256, 256, 0, stream>>>(W, att_src, att_dst, Wp);
    gat_main<<<512, 512, 0, stream>>>(x, Wp, bias, out);
}

// Round 18
// 139.332 us; speedup vs baseline: 1.3010x; 1.0021x over previous
//
#include <hip/hip_runtime.h>
#include <hip/hip_bf16.h>

typedef __bf16 bf16;
typedef __attribute__((ext_vector_type(8))) __bf16 bf16x8;
typedef __attribute__((ext_vector_type(2))) __bf16 bf16x2;
typedef __attribute__((ext_vector_type(4))) float f32x4;
typedef __attribute__((ext_vector_type(4))) unsigned int uint4v;

#define C_NODES 63
#define F_DIM   250
#define NEG_SLOPE 0.2f
#define BS 8               // batches per persistent block; grid 512

// LDS map (74240 B -> 2 blocks/CU):
//   [0, 65520)      SLAB: X as f32, 63 rows x 1040 B stride (260 f32).
//                   DMA fills bytes [0,992) per row; cols 248/249 reg-staged
//                   at [992,1000); cols 250-255 zeroed once at [1000,1024).
//   [65536, 65792)  AS: a_s[64] f32
//   [65792, 66048)  AD: a_d[64] f32
//   [66048, 74240)  ALPHA: alpha[64][64] bf16 (swz, 128 B rows)
#define ROWB      1040
#define SLAB      0
#define OFF_AS    65536
#define OFF_AD    65792
#define ALPHA_B   66048
#define LDS_BYTES 74240

__device__ __forceinline__ int swz(int a) { return a ^ ((a >> 3) & 0x70); }

typedef const __attribute__((address_space(1))) void* gas_t;
typedef __attribute__((address_space(3))) void* las_t;
__device__ __forceinline__ void dma16(const void* g, void* l) {
    __builtin_amdgcn_global_load_lds((gas_t)g, (las_t)l, 16, 0, 0);
}

// lgkm-only barrier: DMA/stores (vmcnt) stay in flight across phases.
__device__ __forceinline__ void bar_lgkm() {
    asm volatile("s_waitcnt lgkmcnt(0)" ::: "memory");
    __builtin_amdgcn_s_barrier();
    __builtin_amdgcn_sched_barrier(0);
}

// Pack W (250x250 f32) into bf16 MFMA-B fragment order, padded to 256x256.
// Columns 250/251 hold ws = W@att_src and wd = W@att_dst, so GEMM1 emits the
// per-node scores a_s, a_d directly. Rows k>=250 are zero (kills A-garbage).
extern "C" __global__ __launch_bounds__(256)
void gat_prep(const float* __restrict__ W, const float* __restrict__ att_src,
              const float* __restrict__ att_dst, bf16* __restrict__ Wp) {
    int i = blockIdx.x * 256 + threadIdx.x;   // 0..65535
    int tile = i >> 9;
    int ln   = (i >> 3) & 63;
    int j    = i & 7;
    int kt = tile >> 4, nt = tile & 15;
    int k = kt * 32 + (ln >> 4) * 8 + j;
    int n = nt * 16 + (ln & 15);
    float v = 0.f;
    if (k < F_DIM) {
        if (n < F_DIM) {
            v = W[k * F_DIM + n];
        } else if (n == F_DIM || n == F_DIM + 1) {
            const float* att = (n == F_DIM) ? att_src : att_dst;
            float s = 0.f;
            for (int o = 0; o < F_DIM; ++o) s = fmaf(W[k * F_DIM + o], att[o], s);
            v = s;
        }
    }
    Wp[i] = (bf16)v;
}

// 512 threads = 8 waves; wave w owns output cols [w*32, w*32+32).
// r17 pipeline + anti-phase skew: one block of each co-resident pair sleeps
// ~8.1K cycles at entry so the two blocks' resource-disjoint phases
// (LDS-bound GEMM1 vs trans-bound softmax vs store-bound epilogue) overlap
// instead of phase-locking.
extern "C" __global__ __launch_bounds__(512, 4)
void gat_main(const float* __restrict__ x, const bf16* __restrict__ Wp,
              const float* __restrict__ bias, float* __restrict__ out)
{
    __shared__ __align__(16) unsigned char smem[LDS_BYTES];
    const int tid  = threadIdx.x;
    const int lane = tid & 63;
    const int w    = tid >> 6;        // wave id 0..7
    const int fl   = lane & 15;
    const int fh   = lane >> 4;
    const int b0   = blockIdx.x * BS;

    // De-phase co-resident block pairs. Covers both plausible pairings:
    // consecutive (bit0 differs) and b/b+256 (bit8 differs).
    if ((blockIdx.x ^ (blockIdx.x >> 8)) & 1)
        asm volatile("s_sleep 127");   // ~8128 cycles ~ 1/3 batch period

    const bf16x8* wpv = (const bf16x8*)Wp;

    // bias (2 regs, held)
    float bv0, bv1;
    { int f = w * 32 + fl;      bv0 = (f < F_DIM) ? bias[f] : 0.f;
      f += 16;                  bv1 = (f < F_DIM) ? bias[f] : 0.f; }

    // zero cols 250-255 of every slab row (once; DMA/tail never re-dirty)
    if (tid < 63) {
        *(unsigned long long*)(smem + SLAB + tid * ROWB + 1000) = 0ull;
        *(f32x4*)(smem + SLAB + tid * ROWB + 1008) = (f32x4){0.f, 0.f, 0.f, 0.f};
    }

    // prime batch b0: DMA rows (wave w stages rows w*8..w*8+7) + reg tail
    {
        const float* xb = x + (size_t)b0 * (C_NODES * F_DIM);
        float2 tl0 = {0.f, 0.f};
        if (tid < 63) tl0 = *(const float2*)(xb + tid * F_DIM + 248);
#pragma unroll
        for (int rr = 0; rr < 8; ++rr) {
            int r = w * 8 + rr;
            if (r < 63 && lane < 62)
                dma16(xb + r * F_DIM + lane * 4, smem + SLAB + r * ROWB);
        }
        if (tid < 63) *(float2*)(smem + SLAB + tid * ROWB + 992) = tl0;
    }
    asm volatile("s_waitcnt vmcnt(0)" ::: "memory");
    bar_lgkm();      // slab[b0] ready

#pragma unroll 1
    for (int i = 0; i < BS; ++i) {
        const int b = b0 + i;
        const float* xnext = x + (size_t)(b + 1) * (C_NODES * F_DIM);

        // tail cols 248/249 of b+1: load EARLY so its wait is vmcnt(N), not 0
        float2 tl = {0.f, 0.f};
        if (i + 1 < BS && tid < 63) tl = *(const float2*)(xnext + tid * F_DIM + 248);

        // ---- A: GEMM1  H'[64][256] = X @ Wp ; cols 250/251 = a_s/a_d;
        //         w7 writes AS/AD before bar1 ----
        f32x4 gacc[4][2];
#pragma unroll
        for (int mt = 0; mt < 4; ++mt) {
            gacc[mt][0] = (f32x4){0.f, 0.f, 0.f, 0.f};
            gacc[mt][1] = (f32x4){0.f, 0.f, 0.f, 0.f};
        }
#pragma unroll 2
        for (int kt = 0; kt < 8; ++kt) {
            bf16x8 bw0 = wpv[(kt * 16 + w * 2)     * 64 + lane];
            bf16x8 bw1 = wpv[(kt * 16 + w * 2 + 1) * 64 + lane];
#pragma unroll
            for (int mt = 0; mt < 4; ++mt) {
                int row = mt * 16 + fl;
                bf16x8 af;
                if (row < C_NODES) {
                    const f32x4* p = (const f32x4*)(smem + SLAB + row * ROWB + kt * 128 + fh * 32);
                    f32x4 lo = p[0], hi = p[1];
                    af = (bf16x8){ (bf16)lo.x, (bf16)lo.y, (bf16)lo.z, (bf16)lo.w,
                                   (bf16)hi.x, (bf16)hi.y, (bf16)hi.z, (bf16)hi.w };
                } else {
                    af = (bf16x8){(bf16)0.f,(bf16)0.f,(bf16)0.f,(bf16)0.f,
                                  (bf16)0.f,(bf16)0.f,(bf16)0.f,(bf16)0.f};
                }
                gacc[mt][0] = __builtin_amdgcn_mfma_f32_16x16x32_bf16(af, bw0, gacc[mt][0], 0, 0, 0);
                gacc[mt][1] = __builtin_amdgcn_mfma_f32_16x16x32_bf16(af, bw1, gacc[mt][1], 0, 0, 0);
            }
        }
        if (w == 7 && (fl == 10 || fl == 11)) {      // cols 250 / 251
            float* dst = (float*)(smem + (fl == 10 ? OFF_AS : OFF_AD));
#pragma unroll
            for (int mt = 0; mt < 4; ++mt) {
                f32x4 v = gacc[mt][1];
#pragma unroll
                for (int q = 0; q < 4; ++q) dst[mt * 16 + fh * 4 + q] = v[q];
            }
        }
        bar_lgkm();   // bar1: slab reads + AS/AD writes done

        // ---- B: DMA(b+1); pack+transpose H; softmax; tail write; bar2 ----
        if (i + 1 < BS) {
#pragma unroll
            for (int rr = 0; rr < 8; ++rr) {
                int r = w * 8 + rr;
                if (r < 63 && lane < 62)
                    dma16(xnext + r * F_DIM + lane * 4, smem + SLAB + r * ROWB);
            }
        }
        // pack H C-frags to bf16 pairs, shuffle-transpose to GEMM2 B-frags
        unsigned int pk[4][2][2];
#pragma unroll
        for (int mt = 0; mt < 4; ++mt)
#pragma unroll
            for (int nti = 0; nti < 2; ++nti) {
                f32x4 v = gacc[mt][nti];
                bf16x2 p0 = { (bf16)v.x, (bf16)v.y };
                bf16x2 p1 = { (bf16)v.z, (bf16)v.w };
                pk[mt][nti][0] = __builtin_bit_cast(unsigned int, p0);
                pk[mt][nti][1] = __builtin_bit_cast(unsigned int, p1);
            }
        const int LA = ((fh & 1) << 5) + fl;
        const int LB = LA + 16;
        const bool fhHi = (fh & 2) != 0;
        uint4v hb[2][2];
#pragma unroll
        for (int nti = 0; nti < 2; ++nti)
#pragma unroll
            for (int kt2 = 0; kt2 < 2; ++kt2) {
                unsigned int u[4];
#pragma unroll
                for (int h = 0; h < 2; ++h) {
                    unsigned int a0 = __shfl(pk[kt2 * 2][nti][h],     LA);
                    unsigned int a1 = __shfl(pk[kt2 * 2 + 1][nti][h], LA);
                    u[h] = fhHi ? a1 : a0;
                    unsigned int c0 = __shfl(pk[kt2 * 2][nti][h],     LB);
                    unsigned int c1 = __shfl(pk[kt2 * 2 + 1][nti][h], LB);
                    u[2 + h] = fhHi ? c1 : c0;
                }
                hb[nti][kt2] = (uint4v){u[0], u[1], u[2], u[3]};
            }
        // softmax (block-wide, once): thread=(d=tid>>3, c=tid&7)
        {
            const float* AS  = (const float*)(smem + OFF_AS);
            const float* ADp = (const float*)(smem + OFF_AD);
            int d = tid >> 3;
            int c = tid & 7;
            float ad_v = ADp[d];
            f32x4 a0 = *(const f32x4*)(AS + c * 8);
            f32x4 a1 = *(const f32x4*)(AS + c * 8 + 4);
            float p[8];
#pragma unroll
            for (int k = 0; k < 4; ++k) {
                float e;
                e = a0[k] + ad_v; p[k]     = (e > 0.f) ? e : NEG_SLOPE * e;
                e = a1[k] + ad_v; p[4 + k] = (e > 0.f) ? e : NEG_SLOPE * e;
            }
            if (c == 7) p[7] = -3.0e38f;   // s=63 excluded (63 sources)
            float md = p[0];
#pragma unroll
            for (int k = 1; k < 8; ++k) md = fmaxf(md, p[k]);
            md = fmaxf(md, __shfl_xor(md, 1));
            md = fmaxf(md, __shfl_xor(md, 2));
            md = fmaxf(md, __shfl_xor(md, 4));
            float sum = 0.f;
#pragma unroll
            for (int k = 0; k < 8; ++k) { p[k] = __expf(p[k] - md); sum += p[k]; }
            sum += __shfl_xor(sum, 1);
            sum += __shfl_xor(sum, 2);
            sum += __shfl_xor(sum, 4);
            float rz = 1.f / sum;
            bf16x8 pkv;
#pragma unroll
            for (int k = 0; k < 8; ++k) pkv[k] = (bf16)(p[k] * rz);
            *(bf16x8*)(smem + swz(ALPHA_B + d * 128 + c * 16)) = pkv;
        }
        if (i + 1 < BS && tid < 63)
            *(float2*)(smem + SLAB + tid * ROWB + 992) = tl;
        bar_lgkm();   // bar2: alpha + tail visible (DMA still flying)

        // ---- D: GEMM2 (alpha LDS x transposed-H regs, gacc reused);
        //         stores; vmcnt-gated bar3 ----
#pragma unroll
        for (int mt = 0; mt < 4; ++mt) {
            gacc[mt][0] = (f32x4){0.f, 0.f, 0.f, 0.f};
            gacc[mt][1] = (f32x4){0.f, 0.f, 0.f, 0.f};
        }
#pragma unroll
        for (int ks = 0; ks < 2; ++ks) {
            int kk = ks * 32 + fh * 8;
            bf16x8 h0 = __builtin_bit_cast(bf16x8, hb[0][ks]);
            bf16x8 h1 = __builtin_bit_cast(bf16x8, hb[1][ks]);
#pragma unroll
            for (int mt = 0; mt < 4; ++mt) {
                bf16x8 aal = *(const bf16x8*)(smem + swz(ALPHA_B + (mt * 16 + fl) * 128 + kk * 2));
                gacc[mt][0] = __builtin_amdgcn_mfma_f32_16x16x32_bf16(aal, h0, gacc[mt][0], 0, 0, 0);
                gacc[mt][1] = __builtin_amdgcn_mfma_f32_16x16x32_bf16(aal, h1, gacc[mt][1], 0, 0, 0);
            }
        }
        float* ob = out + (size_t)b * (C_NODES * F_DIM);
#pragma unroll
        for (int mt = 0; mt < 4; ++mt) {
#pragma unroll
            for (int q = 0; q < 4; ++q) {
                int r = mt * 16 + fh * 4 + q;
                if (r < C_NODES) {
                    int f = w * 32 + fl;
                    ob[r * F_DIM + f] = gacc[mt][0][q] + bv0;
                    f += 16;
                    if (f < F_DIM) ob[r * F_DIM + f] = gacc[mt][1][q] + bv1;
                }
            }
        }
        if (i + 1 < BS) {
            // 8 DMA ops are OLDER than the 32 stores just issued: vmcnt(32)
            // == "all DMA landed, stores may keep flying".
            asm volatile("s_waitcnt vmcnt(32)" ::: "memory");
            bar_lgkm();   // bar3: slab[b+1] visible to all waves
        }
    }
}

extern "C" void kernel_launch(void* const* d_in, const int* in_sizes, int n_in,
                              void* d_out, int out_size, void* d_ws, size_t ws_size,
                              hipStream_t stream) {
    const float* x       = (const float*)d_in[0];
    const float* W       = (const float*)d_in[1];
    const float* att_src = (const float*)d_in[2];
    const float* att_dst = (const float*)d_in[3];
    const float* bias    = (const float*)d_in[4];
    float* out = (float*)d_out;
    bf16* Wp = (bf16*)d_ws;   // 65536 bf16 = 128 KB packed W (+score cols)

    gat_prep<<<256, 256, 0, stream>>>(W, att_src, att_dst, Wp);
    gat_main<<<512, 512, 0, stream>>>(x, Wp, bias, out);
}